// Round 7
// baseline (613.808 us; speedup 1.0000x reference)
//
#include <hip/hip_runtime.h>
#include <math.h>

typedef _Float16 f16;
typedef _Float16 f16x2 __attribute__((ext_vector_type(2)));
typedef _Float16 f16x8 __attribute__((ext_vector_type(8)));
typedef __fp16 fp16x2 __attribute__((ext_vector_type(2)));
typedef float f32x4 __attribute__((ext_vector_type(4)));

union F2U { f16x2 h; fp16x2 p; unsigned u; };
union U4H { uint4 q; f16x2 h[4]; f16 f[8]; };

__device__ __forceinline__ f16x2 uAsH(unsigned u) { F2U c; c.u = u; return c.h; }
__device__ __forceinline__ unsigned hAsU(f16x2 h) { F2U c; c.h = h; return c.u; }
__device__ __forceinline__ unsigned pAsU(fp16x2 p) { F2U c; c.p = p; return c.u; }

constexpr size_t PL = (size_t)512 * 512 * 96;

// ---------------------------------------------------------------------------
// K1: fused pointwise 1x1x1 conv as one GEMM [B*N,96] x [96, 288] (q1|k1|v1).
// Output: q1,k1 as [b][n][c] f16 (via LDS repack); v1 as [b][c][n] f16 direct.
// grid 4096 (64-row tiles), block 256 (4 waves, wave = 16 rows x 288 cols).
// ---------------------------------------------------------------------------
__global__ __launch_bounds__(256) void k1_pointwise(
    const float* __restrict__ x,
    const float* __restrict__ wq1, const float* __restrict__ bq1,
    const float* __restrict__ wk1, const float* __restrict__ bk1,
    const float* __restrict__ wv1, const float* __restrict__ bv1,
    f16* __restrict__ q1, f16* __restrict__ k1, f16* __restrict__ v1)
{
    __shared__ __align__(16) char sm[74368];
    f16*   Ah = (f16*)sm;                  // [64][104]
    f16*   Bw = (f16*)(sm + 13312);        // [288][104]
    float* bl = (float*)(sm + 73216);      // [288]
    f16*   rep = (f16*)(sm + 13312);       // overlay on Bw: [64][200]

    const int tid  = threadIdx.x;
    const int tile = blockIdx.x;
    const int bb   = tile >> 3;
    const int n0   = (tile & 7) * 64;
    const float* xb = x + (size_t)tile * 64 * 96;

    // stage A: 64x96 f32 -> f16 [64][104]
    #pragma unroll
    for (int it = 0; it < 6; ++it) {
        int i = tid * 4 + it * 1024;
        float4 v4 = *(const float4*)(xb + i);
        int r = i / 96, c = i % 96;
        f16x2 h01 = { (f16)v4.x, (f16)v4.y };
        f16x2 h23 = { (f16)v4.z, (f16)v4.w };
        uint2 st; st.x = hAsU(h01); st.y = hAsU(h23);
        *(uint2*)(Ah + r * 104 + c) = st;
    }
    // stage B: 3 x [96 out][96 in] f32 -> [288][104] f16
    #pragma unroll
    for (int it = 0; it < 27; ++it) {
        int i = tid * 4 + it * 1024;           // over 27648
        int a = i / 9216, rem = i % 9216;
        int co = rem / 96, ci = rem % 96;
        const float* wsrc = (a == 0) ? wq1 : ((a == 1) ? wk1 : wv1);
        float4 v4 = *(const float4*)(wsrc + rem);
        f16x2 h01 = { (f16)v4.x, (f16)v4.y };
        f16x2 h23 = { (f16)v4.z, (f16)v4.w };
        uint2 st; st.x = hAsU(h01); st.y = hAsU(h23);
        *(uint2*)(Bw + (a * 96 + co) * 104 + ci) = st;
    }
    for (int i = tid; i < 288; i += 256) {
        const float* bsrc = (i < 96) ? bq1 : ((i < 192) ? bk1 : bv1);
        bl[i] = bsrc[i % 96];
    }
    __syncthreads();

    const int wv_ = tid >> 6, lane = tid & 63, lr = lane & 15, lk = lane >> 4;

    f32x4 acc[18];
    #pragma unroll
    for (int i = 0; i < 18; ++i) acc[i] = f32x4{0.f, 0.f, 0.f, 0.f};

    #pragma unroll
    for (int ks = 0; ks < 3; ++ks) {
        f16x8 a = *(const f16x8*)(Ah + (wv_ * 16 + lr) * 104 + ks * 32 + lk * 8);
        #pragma unroll
        for (int cg = 0; cg < 18; ++cg) {
            f16x8 b8 = *(const f16x8*)(Bw + (cg * 16 + lr) * 104 + ks * 32 + lk * 8);
            acc[cg] = __builtin_amdgcn_mfma_f32_16x16x32_f16(a, b8, acc[cg], 0, 0, 0);
        }
    }
    __syncthreads();  // all MFMA reads of Bw done before rep overlays it

    #pragma unroll
    for (int cg = 0; cg < 18; ++cg) {
        float bv = bl[cg * 16 + lr];
        float o0 = acc[cg][0] + bv, o1 = acc[cg][1] + bv;
        float o2 = acc[cg][2] + bv, o3 = acc[cg][3] + bv;
        if (cg >= 12) {
            int c = (cg - 12) * 16 + lr;
            f16x2 h01 = { (f16)o0, (f16)o1 };
            f16x2 h23 = { (f16)o2, (f16)o3 };
            uint2 st; st.x = hAsU(h01); st.y = hAsU(h23);
            *(uint2*)(v1 + ((size_t)bb * 96 + c) * 512 + n0 + wv_ * 16 + lk * 4) = st;
        } else {
            int rr = wv_ * 16 + lk * 4, cc2 = cg * 16 + lr;
            rep[(rr + 0) * 200 + cc2] = (f16)o0;
            rep[(rr + 1) * 200 + cc2] = (f16)o1;
            rep[(rr + 2) * 200 + cc2] = (f16)o2;
            rep[(rr + 3) * 200 + cc2] = (f16)o3;
        }
    }
    __syncthreads();
    #pragma unroll
    for (int it = 0; it < 6; ++it) {
        int i = tid * 8 + it * 2048;            // over [64][192] = 12288
        int r = i / 192, c = i % 192;
        uint4 d4 = *(const uint4*)(rep + r * 200 + c);
        f16* dst = ((c < 96) ? q1 : k1) + ((size_t)bb * 512 + n0 + r) * 96 + (c % 96);
        *(uint4*)dst = d4;
    }
}

// ---------------------------------------------------------------------------
// K2: depthwise 3x3x3 SAME conv, f16. grid (512 batches, 3 convs), block 512.
// ---------------------------------------------------------------------------
__global__ __launch_bounds__(512) void k2_depthwise(
    const float* __restrict__ wqd, const float* __restrict__ bqd,
    const float* __restrict__ wkd, const float* __restrict__ bkd,
    const float* __restrict__ wvd, const float* __restrict__ bvd,
    const f16* __restrict__ q1, const f16* __restrict__ k1, const f16* __restrict__ v1,
    f16* __restrict__ qo, f16* __restrict__ ko, f16* __restrict__ vo)
{
    __shared__ __align__(16) char sm[112128];
    const int tid = threadIdx.x;
    const int b = blockIdx.x;
    const int which = blockIdx.y;

    if (which < 2) {
        f16*      slab = (f16*)sm;                   // [512][104]
        unsigned* wdh  = (unsigned*)(sm + 106496);   // [27][48] u32 = [27][96] f16
        float*    bl   = (float*)(sm + 111680);      // [96]
        const f16* sb = ((which == 0) ? q1 : k1) + (size_t)b * 512 * 96;
        const float* wg = (which == 0) ? wqd : wkd;
        const float* bg = (which == 0) ? bqd : bkd;

        #pragma unroll
        for (int it = 0; it < 12; ++it) {
            int i = tid * 8 + it * 4096;             // f16 idx over [512][96]
            int r = i / 96, c = i % 96;
            *(uint4*)(slab + r * 104 + c) = *(const uint4*)(sb + i);
        }
        for (int ii = tid; ii < 2592; ii += 512) {
            int c = ii / 27, t2 = ii % 27;
            ((f16*)wdh)[t2 * 96 + c] = (f16)wg[ii];
        }
        if (tid < 96) bl[tid] = bg[tid];
        __syncthreads();

        const int pos = tid;
        const int d = pos >> 6, h = (pos >> 3) & 7, w = pos & 7;
        int npoff[27]; unsigned vmask[27];
        #pragma unroll
        for (int kd = 0; kd < 3; ++kd)
        #pragma unroll
        for (int kh = 0; kh < 3; ++kh)
        #pragma unroll
        for (int kw = 0; kw < 3; ++kw) {
            int t2 = kd * 9 + kh * 3 + kw;
            int d2 = d + kd - 1, h2 = h + kh - 1, w2 = w + kw - 1;
            bool valid = ((unsigned)d2 < 8u) && ((unsigned)h2 < 8u) && ((unsigned)w2 < 8u);
            int np = d2 * 64 + h2 * 8 + w2;
            npoff[t2] = valid ? np * 104 : 0;
            vmask[t2] = valid ? 0xFFFFFFFFu : 0u;
        }
        f16* outb = ((which == 0) ? qo : ko) + (size_t)b * 512 * 96;
        #pragma unroll
        for (int cc = 0; cc < 12; ++cc) {
            f16x2 a0[4], a1[4], a2[4];
            #pragma unroll
            for (int p = 0; p < 4; ++p) {
                a0[p] = f16x2{0, 0}; a1[p] = f16x2{0, 0}; a2[p] = f16x2{0, 0};
            }
            #pragma unroll
            for (int t2 = 0; t2 < 27; ++t2) {
                U4H rw; rw.q = *(const uint4*)(slab + npoff[t2] + cc * 8);
                unsigned vm = vmask[t2];
                #pragma unroll
                for (int p = 0; p < 4; ++p) {
                    f16x2 w2 = uAsH(wdh[t2 * 48 + cc * 4 + p] & vm);
                    if (t2 / 9 == 0)      a0[p] = rw.h[p] * w2 + a0[p];
                    else if (t2 / 9 == 1) a1[p] = rw.h[p] * w2 + a1[p];
                    else                  a2[p] = rw.h[p] * w2 + a2[p];
                }
            }
            unsigned ow[4];
            #pragma unroll
            for (int p = 0; p < 4; ++p) {
                float lo = (float)a0[p].x + (float)a1[p].x + (float)a2[p].x + bl[cc * 8 + 2 * p];
                float hi = (float)a0[p].y + (float)a1[p].y + (float)a2[p].y + bl[cc * 8 + 2 * p + 1];
                f16x2 hp = { (f16)lo, (f16)hi };
                ow[p] = hAsU(hp);
            }
            *(uint4*)(outb + (size_t)pos * 96 + cc * 8) = make_uint4(ow[0], ow[1], ow[2], ow[3]);
        }
    } else {
        f16*      slab = (f16*)sm;                   // [96][512] linear
        unsigned* wdp  = (unsigned*)(sm + 98304);    // [96][27] {w,w} pairs
        float*    bl   = (float*)(sm + 108672);      // [96]
        const f16* sb = v1 + (size_t)b * 96 * 512;

        #pragma unroll
        for (int it = 0; it < 12; ++it) {
            int i = tid * 8 + it * 4096;
            *(uint4*)(slab + i) = *(const uint4*)(sb + i);
        }
        for (int ii = tid; ii < 2592; ii += 512) {
            int c = ii / 27, t2 = ii % 27;
            f16 hh = (f16)wvd[ii];
            f16x2 hp = { hh, hh };
            wdp[c * 27 + t2] = hAsU(hp);
        }
        if (tid < 96) bl[tid] = bvd[tid];
        __syncthreads();

        f16* outb = vo + (size_t)b * 96 * 512;
        #pragma unroll
        for (int j = 0; j < 12; ++j) {
            int u = tid + j * 512;
            int c = u >> 6, dh = u & 63;
            int dd = dh >> 3, hh2 = dh & 7;
            f16x2 A0[4], A1[4], A2[4];
            #pragma unroll
            for (int p = 0; p < 4; ++p) {
                A0[p] = f16x2{0, 0}; A1[p] = f16x2{0, 0}; A2[p] = f16x2{0, 0};
            }
            #pragma unroll
            for (int kd = 0; kd < 3; ++kd) {
                int d2 = dd + kd - 1;
                unsigned vd_ = ((unsigned)d2 < 8u) ? 0xFFFFFFFFu : 0u;
                #pragma unroll
                for (int kh = 0; kh < 3; ++kh) {
                    int h2 = hh2 + kh - 1;
                    unsigned vm = ((((unsigned)h2 < 8u) ? 0xFFFFFFFFu : 0u) & vd_);
                    int rowoff = vm ? ((d2 * 8 + h2) * 8) : 0;
                    uint4 rw = *(const uint4*)(slab + c * 512 + rowoff);
                    unsigned r0 = rw.x, r1 = rw.y, r2 = rw.z, r3 = rw.w;
                    unsigned ms0 = r0 << 16;
                    unsigned ms1 = (r1 << 16) | (r0 >> 16);
                    unsigned ms2 = (r2 << 16) | (r1 >> 16);
                    unsigned ms3 = (r3 << 16) | (r2 >> 16);
                    unsigned ms4 = r3 >> 16;
                    int t0 = kd * 9 + kh * 3;
                    f16x2 w0 = uAsH(wdp[c * 27 + t0]     & vm);
                    f16x2 w1 = uAsH(wdp[c * 27 + t0 + 1] & vm);
                    f16x2 w2 = uAsH(wdp[c * 27 + t0 + 2] & vm);
                    f16x2* acc = (kd == 0) ? A0 : ((kd == 1) ? A1 : A2);
                    acc[0] = uAsH(ms0) * w0 + acc[0];
                    acc[1] = uAsH(ms1) * w0 + acc[1];
                    acc[2] = uAsH(ms2) * w0 + acc[2];
                    acc[3] = uAsH(ms3) * w0 + acc[3];
                    acc[0] = uAsH(r0) * w1 + acc[0];
                    acc[1] = uAsH(r1) * w1 + acc[1];
                    acc[2] = uAsH(r2) * w1 + acc[2];
                    acc[3] = uAsH(r3) * w1 + acc[3];
                    acc[0] = uAsH(ms1) * w2 + acc[0];
                    acc[1] = uAsH(ms2) * w2 + acc[1];
                    acc[2] = uAsH(ms3) * w2 + acc[2];
                    acc[3] = uAsH(ms4) * w2 + acc[3];
                }
            }
            float bv = bl[c];
            unsigned ow[4];
            #pragma unroll
            for (int p = 0; p < 4; ++p) {
                float lo = (float)A0[p].x + (float)A1[p].x + (float)A2[p].x + bv;
                float hi = (float)A0[p].y + (float)A1[p].y + (float)A2[p].y + bv;
                f16x2 hp = { (f16)lo, (f16)hi };
                ow[p] = hAsU(hp);
            }
            *(uint4*)(outb + c * 512 + dh * 8) = make_uint4(ow[0], ow[1], ow[2], ow[3]);
        }
    }
}

// ---------------------------------------------------------------------------
// K3 v3: two-pass softmax attention, zero K/V staging, no barriers.
// Pass 1: all QK^T MFMAs, running in-register max only (no cross-tile deps).
// Pass 2: recompute QK^T per tile (K is cache-hot), exp with FIXED global max
// (no rescale chain), P->LDS (per-wave double buffer), PV MFMA. Tiles fully
// independent -> deep ILP. l = in-register scalar sum + 2 shuffles.
// grid 4096 (XCD-swizzled), block 256 (4 independent waves x 16 q-rows).
// Q,K: [b][n][c]; V: [b][c][n]. Out fp32 [b][n][c].
// ---------------------------------------------------------------------------
__global__ __launch_bounds__(256) void k3_attn(
    const f16* __restrict__ qF, const f16* __restrict__ kF, const f16* __restrict__ vF,
    float* __restrict__ outp)
{
    __shared__ __align__(16) f16 ps[4 * 2 * 1152];   // [wave][buf][16][72] = 18432 B

    const int tid = threadIdx.x;
    // XCD-friendly decode: a batch's 8 q-tiles share (lin & 7) -> same XCD.
    const int lin = blockIdx.x;
    const int g = lin >> 6, rem = lin & 63;
    const int qt = rem >> 3;
    const int b = g * 8 + (rem & 7);

    const int wv_ = tid >> 6, lane = tid & 63, lr = lane & 15, lk = lane >> 4;

    const f16* qg = qF + ((size_t)b * 512 + qt * 64) * 96;
    const f16* kg = kF + (size_t)b * 512 * 96;
    const f16* vg = vF + (size_t)b * 96 * 512;

    const float scl = 0.14724447f;       // log2(e)/sqrt(96), applied post-MFMA

    // Q fragments straight from global, once (coalesced: 4 lanes per 64B line)
    f16x8 qf[3];
    #pragma unroll
    for (int ks3 = 0; ks3 < 3; ++ks3)
        qf[ks3] = *(const f16x8*)(qg + (wv_ * 16 + lr) * 96 + ks3 * 32 + lk * 8);

    // ---- pass 1: global row max (zero inter-tile dependencies) ----
    float mx = -1e30f;
    for (int t = 0; t < 8; ++t) {
        const f16* kt = kg + t * 6144;
        f32x4 sa[4];
        #pragma unroll
        for (int f = 0; f < 4; ++f) sa[f] = f32x4{0.f, 0.f, 0.f, 0.f};
        #pragma unroll
        for (int ks3 = 0; ks3 < 3; ++ks3) {
            #pragma unroll
            for (int f = 0; f < 4; ++f) {
                f16x8 kf = *(const f16x8*)(kt + (f * 16 + lr) * 96 + ks3 * 32 + lk * 8);
                sa[f] = __builtin_amdgcn_mfma_f32_16x16x32_f16(kf, qf[ks3], sa[f], 0, 0, 0);
            }
        }
        #pragma unroll
        for (int f = 0; f < 4; ++f)
            mx = fmaxf(mx, fmaxf(fmaxf(sa[f][0], sa[f][1]), fmaxf(sa[f][2], sa[f][3])));
    }
    mx = fmaxf(mx, __shfl_xor(mx, 16));
    mx = fmaxf(mx, __shfl_xor(mx, 32));

    // opaque touch on qf: pass-2 MFMAs must not CSE with pass-1 results
    #pragma unroll
    for (int i = 0; i < 3; ++i) asm volatile("" : "+v"(qf[i]));

    // ---- pass 2: exp with fixed max, P->LDS, PV. Tiles independent. ----
    float sum_p = 0.f;
    f32x4 accO[6];
    #pragma unroll
    for (int cg = 0; cg < 6; ++cg) accO[cg] = f32x4{0.f, 0.f, 0.f, 0.f};

    for (int t = 0; t < 8; ++t) {
        const f16* kt = kg + t * 6144;
        f32x4 sa[4];
        #pragma unroll
        for (int f = 0; f < 4; ++f) sa[f] = f32x4{0.f, 0.f, 0.f, 0.f};
        #pragma unroll
        for (int ks3 = 0; ks3 < 3; ++ks3) {
            #pragma unroll
            for (int f = 0; f < 4; ++f) {
                f16x8 kf = *(const f16x8*)(kt + (f * 16 + lr) * 96 + ks3 * 32 + lk * 8);
                sa[f] = __builtin_amdgcn_mfma_f32_16x16x32_f16(kf, qf[ks3], sa[f], 0, 0, 0);
            }
        }
        f16* pswt = ps + wv_ * 2304 + (t & 1) * 1152;   // per-wave [16][72]
        unsigned* psw32 = (unsigned*)pswt;
        #pragma unroll
        for (int f = 0; f < 4; ++f) {
            #pragma unroll
            for (int rp = 0; rp < 2; ++rp) {
                float e0 = __builtin_amdgcn_exp2f((sa[f][2 * rp] - mx) * scl);
                float e1 = __builtin_amdgcn_exp2f((sa[f][2 * rp + 1] - mx) * scl);
                sum_p += e0 + e1;
                psw32[lr * 36 + f * 8 + lk * 2 + rp] =
                    pAsU(__builtin_amdgcn_cvt_pkrtz(e0, e1));
            }
        }
        // O^T += V^T P^T  (V fragments straight from global, independent)
        #pragma unroll
        for (int ks2 = 0; ks2 < 2; ++ks2) {
            f16x8 pb = *(const f16x8*)(pswt + lr * 72 + ks2 * 32 + lk * 8);
            #pragma unroll
            for (int cg = 0; cg < 6; ++cg) {
                f16x8 vb = *(const f16x8*)(vg + (size_t)(cg * 16 + lr) * 512
                                              + t * 64 + ks2 * 32 + lk * 8);
                accO[cg] = __builtin_amdgcn_mfma_f32_16x16x32_f16(vb, pb, accO[cg], 0, 0, 0);
            }
        }
    }
    sum_p += __shfl_xor(sum_p, 16);
    sum_p += __shfl_xor(sum_p, 32);

    // epilogue: direct fragment stores, O[q=lr][c=cg*16+lk*4+r] (64B/row segs)
    const float inv = 1.0f / sum_p;
    float* og = outp + ((size_t)b * 512 + qt * 64 + wv_ * 16 + lr) * 96;
    #pragma unroll
    for (int cg = 0; cg < 6; ++cg) {
        float4 o4 = make_float4(accO[cg][0] * inv, accO[cg][1] * inv,
                                accO[cg][2] * inv, accO[cg][3] * inv);
        *(float4*)(og + cg * 16 + lk * 4) = o4;
    }
}

extern "C" void kernel_launch(void* const* d_in, const int* in_sizes, int n_in,
                              void* d_out, int out_size, void* d_ws, size_t ws_size,
                              hipStream_t stream) {
    const float* x   = (const float*)d_in[0];
    const float* wq1 = (const float*)d_in[1];
    const float* bq1 = (const float*)d_in[2];
    const float* wk1 = (const float*)d_in[3];
    const float* bk1 = (const float*)d_in[4];
    const float* wv1 = (const float*)d_in[5];
    const float* bv1 = (const float*)d_in[6];
    const float* wqd = (const float*)d_in[7];
    const float* bqd = (const float*)d_in[8];
    const float* wkd = (const float*)d_in[9];
    const float* bkd = (const float*)d_in[10];
    const float* wvd = (const float*)d_in[11];
    const float* bvd = (const float*)d_in[12];

    f16* ws = (f16*)d_ws;
    f16* q1 = ws;
    f16* k1 = ws + PL;
    f16* v1 = ws + 2 * PL;
    f16* q  = ws + 3 * PL;
    f16* k  = ws + 4 * PL;
    f16* v  = ws + 5 * PL;

    k1_pointwise<<<4096, 256, 0, stream>>>(x, wq1, bq1, wk1, bk1, wv1, bv1, q1, k1, v1);
    k2_depthwise<<<dim3(512, 3), 512, 0, stream>>>(wqd, bqd, wkd, bkd, wvd, bvd,
                                                   q1, k1, v1, q, k, v);
    k3_attn<<<4096, 256, 0, stream>>>(q, k, v, (float*)d_out);
}

// Round 8
// 378.502 us; speedup vs baseline: 1.6217x; 1.6217x over previous
//
#include <hip/hip_runtime.h>
#include <math.h>

typedef _Float16 f16;
typedef _Float16 f16x2 __attribute__((ext_vector_type(2)));
typedef _Float16 f16x8 __attribute__((ext_vector_type(8)));
typedef __fp16 fp16x2 __attribute__((ext_vector_type(2)));
typedef float f32x4 __attribute__((ext_vector_type(4)));

union F2U { f16x2 h; fp16x2 p; unsigned u; };
union U4H { uint4 q; f16x2 h[4]; f16 f[8]; };

__device__ __forceinline__ f16x2 uAsH(unsigned u) { F2U c; c.u = u; return c.h; }
__device__ __forceinline__ unsigned hAsU(f16x2 h) { F2U c; c.h = h; return c.u; }
__device__ __forceinline__ unsigned pAsU(fp16x2 p) { F2U c; c.p = p; return c.u; }

constexpr size_t PL = (size_t)512 * 512 * 96;

// ---------------------------------------------------------------------------
// K1: fused pointwise 1x1x1 conv as one GEMM [B*N,96] x [96, 288] (q1|k1|v1).
// Output: q1,k1 as [b][n][c] f16 (via LDS repack); v1 as [b][c][n] f16 direct.
// grid 4096 (64-row tiles), block 256 (4 waves, wave = 16 rows x 288 cols).
// ---------------------------------------------------------------------------
__global__ __launch_bounds__(256) void k1_pointwise(
    const float* __restrict__ x,
    const float* __restrict__ wq1, const float* __restrict__ bq1,
    const float* __restrict__ wk1, const float* __restrict__ bk1,
    const float* __restrict__ wv1, const float* __restrict__ bv1,
    f16* __restrict__ q1, f16* __restrict__ k1, f16* __restrict__ v1)
{
    __shared__ __align__(16) char sm[74368];
    f16*   Ah = (f16*)sm;                  // [64][104]
    f16*   Bw = (f16*)(sm + 13312);        // [288][104]
    float* bl = (float*)(sm + 73216);      // [288]
    f16*   rep = (f16*)(sm + 13312);       // overlay on Bw: [64][200]

    const int tid  = threadIdx.x;
    const int tile = blockIdx.x;
    const int bb   = tile >> 3;
    const int n0   = (tile & 7) * 64;
    const float* xb = x + (size_t)tile * 64 * 96;

    // stage A: 64x96 f32 -> f16 [64][104]
    #pragma unroll
    for (int it = 0; it < 6; ++it) {
        int i = tid * 4 + it * 1024;
        float4 v4 = *(const float4*)(xb + i);
        int r = i / 96, c = i % 96;
        f16x2 h01 = { (f16)v4.x, (f16)v4.y };
        f16x2 h23 = { (f16)v4.z, (f16)v4.w };
        uint2 st; st.x = hAsU(h01); st.y = hAsU(h23);
        *(uint2*)(Ah + r * 104 + c) = st;
    }
    // stage B: 3 x [96 out][96 in] f32 -> [288][104] f16
    #pragma unroll
    for (int it = 0; it < 27; ++it) {
        int i = tid * 4 + it * 1024;           // over 27648
        int a = i / 9216, rem = i % 9216;
        int co = rem / 96, ci = rem % 96;
        const float* wsrc = (a == 0) ? wq1 : ((a == 1) ? wk1 : wv1);
        float4 v4 = *(const float4*)(wsrc + rem);
        f16x2 h01 = { (f16)v4.x, (f16)v4.y };
        f16x2 h23 = { (f16)v4.z, (f16)v4.w };
        uint2 st; st.x = hAsU(h01); st.y = hAsU(h23);
        *(uint2*)(Bw + (a * 96 + co) * 104 + ci) = st;
    }
    for (int i = tid; i < 288; i += 256) {
        const float* bsrc = (i < 96) ? bq1 : ((i < 192) ? bk1 : bv1);
        bl[i] = bsrc[i % 96];
    }
    __syncthreads();

    const int wv_ = tid >> 6, lane = tid & 63, lr = lane & 15, lk = lane >> 4;

    f32x4 acc[18];
    #pragma unroll
    for (int i = 0; i < 18; ++i) acc[i] = f32x4{0.f, 0.f, 0.f, 0.f};

    #pragma unroll
    for (int ks = 0; ks < 3; ++ks) {
        f16x8 a = *(const f16x8*)(Ah + (wv_ * 16 + lr) * 104 + ks * 32 + lk * 8);
        #pragma unroll
        for (int cg = 0; cg < 18; ++cg) {
            f16x8 b8 = *(const f16x8*)(Bw + (cg * 16 + lr) * 104 + ks * 32 + lk * 8);
            acc[cg] = __builtin_amdgcn_mfma_f32_16x16x32_f16(a, b8, acc[cg], 0, 0, 0);
        }
    }
    __syncthreads();  // all MFMA reads of Bw done before rep overlays it

    #pragma unroll
    for (int cg = 0; cg < 18; ++cg) {
        float bv = bl[cg * 16 + lr];
        float o0 = acc[cg][0] + bv, o1 = acc[cg][1] + bv;
        float o2 = acc[cg][2] + bv, o3 = acc[cg][3] + bv;
        if (cg >= 12) {
            int c = (cg - 12) * 16 + lr;
            f16x2 h01 = { (f16)o0, (f16)o1 };
            f16x2 h23 = { (f16)o2, (f16)o3 };
            uint2 st; st.x = hAsU(h01); st.y = hAsU(h23);
            *(uint2*)(v1 + ((size_t)bb * 96 + c) * 512 + n0 + wv_ * 16 + lk * 4) = st;
        } else {
            int rr = wv_ * 16 + lk * 4, cc2 = cg * 16 + lr;
            rep[(rr + 0) * 200 + cc2] = (f16)o0;
            rep[(rr + 1) * 200 + cc2] = (f16)o1;
            rep[(rr + 2) * 200 + cc2] = (f16)o2;
            rep[(rr + 3) * 200 + cc2] = (f16)o3;
        }
    }
    __syncthreads();
    #pragma unroll
    for (int it = 0; it < 6; ++it) {
        int i = tid * 8 + it * 2048;            // over [64][192] = 12288
        int r = i / 192, c = i % 192;
        uint4 d4 = *(const uint4*)(rep + r * 200 + c);
        f16* dst = ((c < 96) ? q1 : k1) + ((size_t)bb * 512 + n0 + r) * 96 + (c % 96);
        *(uint4*)dst = d4;
    }
}

// ---------------------------------------------------------------------------
// K2: depthwise 3x3x3 SAME conv, f16. grid (512 batches, 3 convs), block 512.
// ---------------------------------------------------------------------------
__global__ __launch_bounds__(512) void k2_depthwise(
    const float* __restrict__ wqd, const float* __restrict__ bqd,
    const float* __restrict__ wkd, const float* __restrict__ bkd,
    const float* __restrict__ wvd, const float* __restrict__ bvd,
    const f16* __restrict__ q1, const f16* __restrict__ k1, const f16* __restrict__ v1,
    f16* __restrict__ qo, f16* __restrict__ ko, f16* __restrict__ vo)
{
    __shared__ __align__(16) char sm[112128];
    const int tid = threadIdx.x;
    const int b = blockIdx.x;
    const int which = blockIdx.y;

    if (which < 2) {
        f16*      slab = (f16*)sm;                   // [512][104]
        unsigned* wdh  = (unsigned*)(sm + 106496);   // [27][48] u32 = [27][96] f16
        float*    bl   = (float*)(sm + 111680);      // [96]
        const f16* sb = ((which == 0) ? q1 : k1) + (size_t)b * 512 * 96;
        const float* wg = (which == 0) ? wqd : wkd;
        const float* bg = (which == 0) ? bqd : bkd;

        #pragma unroll
        for (int it = 0; it < 12; ++it) {
            int i = tid * 8 + it * 4096;             // f16 idx over [512][96]
            int r = i / 96, c = i % 96;
            *(uint4*)(slab + r * 104 + c) = *(const uint4*)(sb + i);
        }
        for (int ii = tid; ii < 2592; ii += 512) {
            int c = ii / 27, t2 = ii % 27;
            ((f16*)wdh)[t2 * 96 + c] = (f16)wg[ii];
        }
        if (tid < 96) bl[tid] = bg[tid];
        __syncthreads();

        const int pos = tid;
        const int d = pos >> 6, h = (pos >> 3) & 7, w = pos & 7;
        int npoff[27]; unsigned vmask[27];
        #pragma unroll
        for (int kd = 0; kd < 3; ++kd)
        #pragma unroll
        for (int kh = 0; kh < 3; ++kh)
        #pragma unroll
        for (int kw = 0; kw < 3; ++kw) {
            int t2 = kd * 9 + kh * 3 + kw;
            int d2 = d + kd - 1, h2 = h + kh - 1, w2 = w + kw - 1;
            bool valid = ((unsigned)d2 < 8u) && ((unsigned)h2 < 8u) && ((unsigned)w2 < 8u);
            int np = d2 * 64 + h2 * 8 + w2;
            npoff[t2] = valid ? np * 104 : 0;
            vmask[t2] = valid ? 0xFFFFFFFFu : 0u;
        }
        f16* outb = ((which == 0) ? qo : ko) + (size_t)b * 512 * 96;
        #pragma unroll
        for (int cc = 0; cc < 12; ++cc) {
            f16x2 a0[4], a1[4], a2[4];
            #pragma unroll
            for (int p = 0; p < 4; ++p) {
                a0[p] = f16x2{0, 0}; a1[p] = f16x2{0, 0}; a2[p] = f16x2{0, 0};
            }
            #pragma unroll
            for (int t2 = 0; t2 < 27; ++t2) {
                U4H rw; rw.q = *(const uint4*)(slab + npoff[t2] + cc * 8);
                unsigned vm = vmask[t2];
                #pragma unroll
                for (int p = 0; p < 4; ++p) {
                    f16x2 w2 = uAsH(wdh[t2 * 48 + cc * 4 + p] & vm);
                    if (t2 / 9 == 0)      a0[p] = rw.h[p] * w2 + a0[p];
                    else if (t2 / 9 == 1) a1[p] = rw.h[p] * w2 + a1[p];
                    else                  a2[p] = rw.h[p] * w2 + a2[p];
                }
            }
            unsigned ow[4];
            #pragma unroll
            for (int p = 0; p < 4; ++p) {
                float lo = (float)a0[p].x + (float)a1[p].x + (float)a2[p].x + bl[cc * 8 + 2 * p];
                float hi = (float)a0[p].y + (float)a1[p].y + (float)a2[p].y + bl[cc * 8 + 2 * p + 1];
                f16x2 hp = { (f16)lo, (f16)hi };
                ow[p] = hAsU(hp);
            }
            *(uint4*)(outb + (size_t)pos * 96 + cc * 8) = make_uint4(ow[0], ow[1], ow[2], ow[3]);
        }
    } else {
        f16*      slab = (f16*)sm;                   // [96][512] linear
        unsigned* wdp  = (unsigned*)(sm + 98304);    // [96][27] {w,w} pairs
        float*    bl   = (float*)(sm + 108672);      // [96]
        const f16* sb = v1 + (size_t)b * 96 * 512;

        #pragma unroll
        for (int it = 0; it < 12; ++it) {
            int i = tid * 8 + it * 4096;
            *(uint4*)(slab + i) = *(const uint4*)(sb + i);
        }
        for (int ii = tid; ii < 2592; ii += 512) {
            int c = ii / 27, t2 = ii % 27;
            f16 hh = (f16)wvd[ii];
            f16x2 hp = { hh, hh };
            wdp[c * 27 + t2] = hAsU(hp);
        }
        if (tid < 96) bl[tid] = bvd[tid];
        __syncthreads();

        f16* outb = vo + (size_t)b * 96 * 512;
        #pragma unroll
        for (int j = 0; j < 12; ++j) {
            int u = tid + j * 512;
            int c = u >> 6, dh = u & 63;
            int dd = dh >> 3, hh2 = dh & 7;
            f16x2 A0[4], A1[4], A2[4];
            #pragma unroll
            for (int p = 0; p < 4; ++p) {
                A0[p] = f16x2{0, 0}; A1[p] = f16x2{0, 0}; A2[p] = f16x2{0, 0};
            }
            #pragma unroll
            for (int kd = 0; kd < 3; ++kd) {
                int d2 = dd + kd - 1;
                unsigned vd_ = ((unsigned)d2 < 8u) ? 0xFFFFFFFFu : 0u;
                #pragma unroll
                for (int kh = 0; kh < 3; ++kh) {
                    int h2 = hh2 + kh - 1;
                    unsigned vm = ((((unsigned)h2 < 8u) ? 0xFFFFFFFFu : 0u) & vd_);
                    int rowoff = vm ? ((d2 * 8 + h2) * 8) : 0;
                    uint4 rw = *(const uint4*)(slab + c * 512 + rowoff);
                    unsigned r0 = rw.x, r1 = rw.y, r2 = rw.z, r3 = rw.w;
                    unsigned ms0 = r0 << 16;
                    unsigned ms1 = (r1 << 16) | (r0 >> 16);
                    unsigned ms2 = (r2 << 16) | (r1 >> 16);
                    unsigned ms3 = (r3 << 16) | (r2 >> 16);
                    unsigned ms4 = r3 >> 16;
                    int t0 = kd * 9 + kh * 3;
                    f16x2 w0 = uAsH(wdp[c * 27 + t0]     & vm);
                    f16x2 w1 = uAsH(wdp[c * 27 + t0 + 1] & vm);
                    f16x2 w2 = uAsH(wdp[c * 27 + t0 + 2] & vm);
                    f16x2* acc = (kd == 0) ? A0 : ((kd == 1) ? A1 : A2);
                    acc[0] = uAsH(ms0) * w0 + acc[0];
                    acc[1] = uAsH(ms1) * w0 + acc[1];
                    acc[2] = uAsH(ms2) * w0 + acc[2];
                    acc[3] = uAsH(ms3) * w0 + acc[3];
                    acc[0] = uAsH(r0) * w1 + acc[0];
                    acc[1] = uAsH(r1) * w1 + acc[1];
                    acc[2] = uAsH(r2) * w1 + acc[2];
                    acc[3] = uAsH(r3) * w1 + acc[3];
                    acc[0] = uAsH(ms1) * w2 + acc[0];
                    acc[1] = uAsH(ms2) * w2 + acc[1];
                    acc[2] = uAsH(ms3) * w2 + acc[2];
                    acc[3] = uAsH(ms4) * w2 + acc[3];
                }
            }
            float bv = bl[c];
            unsigned ow[4];
            #pragma unroll
            for (int p = 0; p < 4; ++p) {
                float lo = (float)A0[p].x + (float)A1[p].x + (float)A2[p].x + bv;
                float hi = (float)A0[p].y + (float)A1[p].y + (float)A2[p].y + bv;
                f16x2 hp = { (f16)lo, (f16)hi };
                ow[p] = hAsU(hp);
            }
            *(uint4*)(outb + c * 512 + dh * 8) = make_uint4(ow[0], ow[1], ow[2], ow[3]);
        }
    }
}

// ---------------------------------------------------------------------------
// K3 v4: per-batch mega-block. grid 512 (1 block = 1 batch), block 512
// (8 waves x 64 q-rows). K staged in LDS ONCE (shared by all 8 waves);
// V fragments hoisted per tile (reused across 4 q-groups); two-pass fixed-max
// softmax (no inter-tile chains); per-wave P buffer (DS-pipe ordered).
// Q,K: [b][n][c]; V: [b][c][n]. Out fp32 [b][n][c].
// ---------------------------------------------------------------------------
__global__ __launch_bounds__(512) void k3_attn(
    const f16* __restrict__ qF, const f16* __restrict__ kF, const f16* __restrict__ vF,
    float* __restrict__ outp)
{
    __shared__ __align__(16) f16 Ksh[512 * 104];   // 106496 B
    __shared__ __align__(16) f16 Psh[8 * 1152];    // 8 waves x [16 q][72 k] = 18432 B

    const int tid = threadIdx.x;
    const int b = blockIdx.x;
    const int wv_ = tid >> 6, lane = tid & 63, lr = lane & 15, lk = lane >> 4;

    const f16* qg = qF + ((size_t)b * 512 + wv_ * 64) * 96;
    const f16* kg = kF + (size_t)b * 512 * 96;
    const f16* vg = vF + (size_t)b * 96 * 512;

    const float scl = 0.14724447f;   // log2(e)/sqrt(96), applied post-MFMA

    // ---- stage K once: [512][96] -> Ksh[512][104] ----
    #pragma unroll
    for (int it = 0; it < 12; ++it) {
        int i = tid * 8 + it * 4096;
        int r = i / 96, c = i % 96;
        *(uint4*)(Ksh + r * 104 + c) = *(const uint4*)(kg + i);
    }

    // Q fragments for this wave's 4 q-groups (64 rows), from global
    f16x8 qf[4][3];
    #pragma unroll
    for (int qg2 = 0; qg2 < 4; ++qg2)
        #pragma unroll
        for (int ks3 = 0; ks3 < 3; ++ks3)
            qf[qg2][ks3] = *(const f16x8*)(qg + (qg2 * 16 + lr) * 96 + ks3 * 32 + lk * 8);

    __syncthreads();   // K staged

    // ---- pass 1: global row max per q-group ----
    float mx[4] = {-1e30f, -1e30f, -1e30f, -1e30f};
    for (int t = 0; t < 8; ++t) {
        f16x8 kf[3][4];
        #pragma unroll
        for (int ks3 = 0; ks3 < 3; ++ks3)
            #pragma unroll
            for (int f = 0; f < 4; ++f)
                kf[ks3][f] = *(const f16x8*)(Ksh + (t * 64 + f * 16 + lr) * 104 + ks3 * 32 + lk * 8);
        #pragma unroll
        for (int qg2 = 0; qg2 < 4; ++qg2) {
            f32x4 sa[4];
            #pragma unroll
            for (int f = 0; f < 4; ++f) sa[f] = f32x4{0.f, 0.f, 0.f, 0.f};
            #pragma unroll
            for (int ks3 = 0; ks3 < 3; ++ks3)
                #pragma unroll
                for (int f = 0; f < 4; ++f)
                    sa[f] = __builtin_amdgcn_mfma_f32_16x16x32_f16(kf[ks3][f], qf[qg2][ks3], sa[f], 0, 0, 0);
            #pragma unroll
            for (int f = 0; f < 4; ++f)
                mx[qg2] = fmaxf(mx[qg2],
                    fmaxf(fmaxf(sa[f][0], sa[f][1]), fmaxf(sa[f][2], sa[f][3])));
        }
    }
    #pragma unroll
    for (int qg2 = 0; qg2 < 4; ++qg2) {
        mx[qg2] = fmaxf(mx[qg2], __shfl_xor(mx[qg2], 16));
        mx[qg2] = fmaxf(mx[qg2], __shfl_xor(mx[qg2], 32));
    }

    // opaque touch: pass-2 MFMAs must not CSE with pass-1 results
    #pragma unroll
    for (int qg2 = 0; qg2 < 4; ++qg2)
        #pragma unroll
        for (int i = 0; i < 3; ++i) asm volatile("" : "+v"(qf[qg2][i]));

    // ---- pass 2: recompute QK (K LDS-hot), exp with fixed max, PV ----
    float sum_p[4] = {0.f, 0.f, 0.f, 0.f};
    f32x4 accO[4][6];
    #pragma unroll
    for (int qg2 = 0; qg2 < 4; ++qg2)
        #pragma unroll
        for (int cg = 0; cg < 6; ++cg) accO[qg2][cg] = f32x4{0.f, 0.f, 0.f, 0.f};

    f16* psw = Psh + wv_ * 1152;        // per-wave [16][72]
    unsigned* psw32 = (unsigned*)psw;

    for (int t = 0; t < 8; ++t) {
        // hoist V fragments for this tile (reused by all 4 q-groups)
        f16x8 vb[2][6];
        #pragma unroll
        for (int ks2 = 0; ks2 < 2; ++ks2)
            #pragma unroll
            for (int cg = 0; cg < 6; ++cg)
                vb[ks2][cg] = *(const f16x8*)(vg + (size_t)(cg * 16 + lr) * 512
                                                 + t * 64 + ks2 * 32 + lk * 8);
        #pragma unroll
        for (int qg2 = 0; qg2 < 4; ++qg2) {
            f32x4 sa[4];
            #pragma unroll
            for (int f = 0; f < 4; ++f) sa[f] = f32x4{0.f, 0.f, 0.f, 0.f};
            #pragma unroll
            for (int ks3 = 0; ks3 < 3; ++ks3)
                #pragma unroll
                for (int f = 0; f < 4; ++f) {
                    f16x8 kf = *(const f16x8*)(Ksh + (t * 64 + f * 16 + lr) * 104 + ks3 * 32 + lk * 8);
                    sa[f] = __builtin_amdgcn_mfma_f32_16x16x32_f16(kf, qf[qg2][ks3], sa[f], 0, 0, 0);
                }
            // exp with fixed max; P -> per-wave LDS (B-operand layout)
            #pragma unroll
            for (int f = 0; f < 4; ++f) {
                #pragma unroll
                for (int rp = 0; rp < 2; ++rp) {
                    float e0 = __builtin_amdgcn_exp2f((sa[f][2 * rp]     - mx[qg2]) * scl);
                    float e1 = __builtin_amdgcn_exp2f((sa[f][2 * rp + 1] - mx[qg2]) * scl);
                    sum_p[qg2] += e0 + e1;
                    psw32[lr * 36 + f * 8 + lk * 2 + rp] =
                        pAsU(__builtin_amdgcn_cvt_pkrtz(e0, e1));
                }
            }
            // O^T += V^T P^T (DS pipe in-order: reads of this qg2 precede
            // next qg2's overwrites in program order -> single buffer safe)
            #pragma unroll
            for (int ks2 = 0; ks2 < 2; ++ks2) {
                f16x8 pb = *(const f16x8*)(psw + lr * 72 + ks2 * 32 + lk * 8);
                #pragma unroll
                for (int cg = 0; cg < 6; ++cg)
                    accO[qg2][cg] = __builtin_amdgcn_mfma_f32_16x16x32_f16(
                        vb[ks2][cg], pb, accO[qg2][cg], 0, 0, 0);
            }
        }
    }
    #pragma unroll
    for (int qg2 = 0; qg2 < 4; ++qg2) {
        sum_p[qg2] += __shfl_xor(sum_p[qg2], 16);
        sum_p[qg2] += __shfl_xor(sum_p[qg2], 32);
    }

    // ---- epilogue: direct fragment stores O[q][c] ----
    #pragma unroll
    for (int qg2 = 0; qg2 < 4; ++qg2) {
        const float inv = 1.0f / sum_p[qg2];
        float* og = outp + ((size_t)b * 512 + wv_ * 64 + qg2 * 16 + lr) * 96;
        #pragma unroll
        for (int cg = 0; cg < 6; ++cg) {
            float4 o4 = make_float4(accO[qg2][cg][0] * inv, accO[qg2][cg][1] * inv,
                                    accO[qg2][cg][2] * inv, accO[qg2][cg][3] * inv);
            *(float4*)(og + cg * 16 + lk * 4) = o4;
        }
    }
}

extern "C" void kernel_launch(void* const* d_in, const int* in_sizes, int n_in,
                              void* d_out, int out_size, void* d_ws, size_t ws_size,
                              hipStream_t stream) {
    const float* x   = (const float*)d_in[0];
    const float* wq1 = (const float*)d_in[1];
    const float* bq1 = (const float*)d_in[2];
    const float* wk1 = (const float*)d_in[3];
    const float* bk1 = (const float*)d_in[4];
    const float* wv1 = (const float*)d_in[5];
    const float* bv1 = (const float*)d_in[6];
    const float* wqd = (const float*)d_in[7];
    const float* bqd = (const float*)d_in[8];
    const float* wkd = (const float*)d_in[9];
    const float* bkd = (const float*)d_in[10];
    const float* wvd = (const float*)d_in[11];
    const float* bvd = (const float*)d_in[12];

    f16* ws = (f16*)d_ws;
    f16* q1 = ws;
    f16* k1 = ws + PL;
    f16* v1 = ws + 2 * PL;
    f16* q  = ws + 3 * PL;
    f16* k  = ws + 4 * PL;
    f16* v  = ws + 5 * PL;

    k1_pointwise<<<4096, 256, 0, stream>>>(x, wq1, bq1, wk1, bk1, wv1, bv1, q1, k1, v1);
    k2_depthwise<<<dim3(512, 3), 512, 0, stream>>>(wqd, bqd, wkd, bkd, wvd, bvd,
                                                   q1, k1, v1, q, k, v);
    k3_attn<<<512, 512, 0, stream>>>(q, k, v, (float*)d_out);
}

// Round 9
// 329.324 us; speedup vs baseline: 1.8638x; 1.1493x over previous
//
#include <hip/hip_runtime.h>
#include <math.h>

typedef _Float16 f16;
typedef _Float16 f16x2 __attribute__((ext_vector_type(2)));
typedef _Float16 f16x8 __attribute__((ext_vector_type(8)));
typedef __fp16 fp16x2 __attribute__((ext_vector_type(2)));
typedef float f32x4 __attribute__((ext_vector_type(4)));

union F2U { f16x2 h; fp16x2 p; unsigned u; };
union U4H { uint4 q; f16x2 h[4]; f16 f[8]; };

__device__ __forceinline__ f16x2 uAsH(unsigned u) { F2U c; c.u = u; return c.h; }
__device__ __forceinline__ unsigned hAsU(f16x2 h) { F2U c; c.h = h; return c.u; }
__device__ __forceinline__ unsigned pAsU(fp16x2 p) { F2U c; c.p = p; return c.u; }

constexpr size_t PL = (size_t)512 * 512 * 96;

// ---------------------------------------------------------------------------
// K12: fused pointwise(1x1x1, MFMA GEMM) + depthwise(3x3x3 SAME) conv.
// grid (512 batches, 3 convs), block 512 (8 waves). x staged f16 in LDS;
// GEMM held in registers; output (+bias) overwrites the x slab in the layout
// the depthwise phase wants ([pos][ch] for q/k; [ch][pos] stride-520 for v).
// Eliminates the q1/k1/v1 global intermediate entirely.
// Outputs: q,k as [b][n][c]; v as [b][c][n].
// ---------------------------------------------------------------------------
__global__ __launch_bounds__(512) void k12_fused(
    const float* __restrict__ x,
    const float* __restrict__ wq1, const float* __restrict__ bq1,
    const float* __restrict__ wk1, const float* __restrict__ bk1,
    const float* __restrict__ wv1, const float* __restrict__ bv1,
    const float* __restrict__ wqd, const float* __restrict__ bqd,
    const float* __restrict__ wkd, const float* __restrict__ bkd,
    const float* __restrict__ wvd, const float* __restrict__ bvd,
    f16* __restrict__ qo, f16* __restrict__ ko, f16* __restrict__ vo)
{
    __shared__ __align__(16) char sm[137600];
    f16* Xsh = (f16*)sm;                       // [512][104] f16; overlaid post-GEMM
    f16* Wsh = (f16*)(sm + 106496);            // [96][104] f16 pointwise w
    unsigned* wdx = (unsigned*)(sm + 126464);  // q/k: [27][48] u32; v: [96][27] u32
    float* bl1 = (float*)(sm + 136832);        // [96] pointwise bias
    float* bld = (float*)(sm + 137216);        // [96] depthwise bias

    const int tid = threadIdx.x;
    const int b = blockIdx.x;
    const int which = blockIdx.y;
    const int wv_ = tid >> 6, lane = tid & 63, lr = lane & 15, lk = lane >> 4;

    const float* w1 = (which == 0) ? wq1 : ((which == 1) ? wk1 : wv1);
    const float* b1 = (which == 0) ? bq1 : ((which == 1) ? bk1 : bv1);
    const float* wd = (which == 0) ? wqd : ((which == 1) ? wkd : wvd);
    const float* bd = (which == 0) ? bqd : ((which == 1) ? bkd : bvd);

    // ---- stage x (f32->f16), pointwise w, depthwise w, biases ----
    const float* xb = x + (size_t)b * 512 * 96;
    #pragma unroll
    for (int it = 0; it < 24; ++it) {
        int i = (tid + it * 512) * 4;
        float4 v4 = *(const float4*)(xb + i);
        int r = i / 96, c = i % 96;
        f16x2 h01 = { (f16)v4.x, (f16)v4.y };
        f16x2 h23 = { (f16)v4.z, (f16)v4.w };
        uint2 st; st.x = hAsU(h01); st.y = hAsU(h23);
        *(uint2*)(Xsh + r * 104 + c) = st;
    }
    #pragma unroll
    for (int it = 0; it < 5; ++it) {
        int i = (tid + it * 512) * 4;
        if (i < 9216) {
            float4 v4 = *(const float4*)(w1 + i);
            int co = i / 96, ci = i % 96;
            f16x2 h01 = { (f16)v4.x, (f16)v4.y };
            f16x2 h23 = { (f16)v4.z, (f16)v4.w };
            uint2 st; st.x = hAsU(h01); st.y = hAsU(h23);
            *(uint2*)(Wsh + co * 104 + ci) = st;
        }
    }
    if (which < 2) {
        for (int ii = tid; ii < 2592; ii += 512) {
            int c = ii / 27, t2 = ii % 27;
            ((f16*)wdx)[t2 * 96 + c] = (f16)wd[ii];
        }
    } else {
        for (int ii = tid; ii < 2592; ii += 512) {
            int c = ii / 27, t2 = ii % 27;
            f16 hh = (f16)wd[ii];
            f16x2 hp = { hh, hh };
            wdx[c * 27 + t2] = hAsU(hp);
        }
    }
    if (tid < 96) { bl1[tid] = b1[tid]; bld[tid] = bd[tid]; }
    __syncthreads();

    // ---- pointwise GEMM: wave = 64 positions x 96 out-channels ----
    f32x4 acc[4][6];
    #pragma unroll
    for (int qg2 = 0; qg2 < 4; ++qg2)
        #pragma unroll
        for (int cg = 0; cg < 6; ++cg) acc[qg2][cg] = f32x4{0.f, 0.f, 0.f, 0.f};

    #pragma unroll
    for (int ks = 0; ks < 3; ++ks) {
        f16x8 bfr[6];
        #pragma unroll
        for (int cg = 0; cg < 6; ++cg)
            bfr[cg] = *(const f16x8*)(Wsh + (cg * 16 + lr) * 104 + ks * 32 + lk * 8);
        #pragma unroll
        for (int qg2 = 0; qg2 < 4; ++qg2) {
            f16x8 a = *(const f16x8*)(Xsh + (wv_ * 64 + qg2 * 16 + lr) * 104 + ks * 32 + lk * 8);
            #pragma unroll
            for (int cg = 0; cg < 6; ++cg)
                acc[qg2][cg] = __builtin_amdgcn_mfma_f32_16x16x32_f16(a, bfr[cg], acc[qg2][cg], 0, 0, 0);
        }
    }
    __syncthreads();   // all Xsh reads done before overlay

    // ---- write GEMM out (+bias) over the slab in depthwise layout ----
    if (which < 2) {
        // Osh[pos][ch], stride 104 (same region as Xsh)
        #pragma unroll
        for (int qg2 = 0; qg2 < 4; ++qg2) {
            #pragma unroll
            for (int cg = 0; cg < 6; ++cg) {
                float bv = bl1[cg * 16 + lr];
                int base = wv_ * 64 + qg2 * 16 + lk * 4;
                int ch = cg * 16 + lr;
                Xsh[(base + 0) * 104 + ch] = (f16)(acc[qg2][cg][0] + bv);
                Xsh[(base + 1) * 104 + ch] = (f16)(acc[qg2][cg][1] + bv);
                Xsh[(base + 2) * 104 + ch] = (f16)(acc[qg2][cg][2] + bv);
                Xsh[(base + 3) * 104 + ch] = (f16)(acc[qg2][cg][3] + bv);
            }
        }
    } else {
        // Vt[ch][pos], stride 520 (4 consecutive positions -> uint2)
        #pragma unroll
        for (int qg2 = 0; qg2 < 4; ++qg2) {
            #pragma unroll
            for (int cg = 0; cg < 6; ++cg) {
                float bv = bl1[cg * 16 + lr];
                int ch = cg * 16 + lr;
                int pos = wv_ * 64 + qg2 * 16 + lk * 4;
                f16x2 h01 = { (f16)(acc[qg2][cg][0] + bv), (f16)(acc[qg2][cg][1] + bv) };
                f16x2 h23 = { (f16)(acc[qg2][cg][2] + bv), (f16)(acc[qg2][cg][3] + bv) };
                uint2 st; st.x = hAsU(h01); st.y = hAsU(h23);
                *(uint2*)(Xsh + ch * 520 + pos) = st;
            }
        }
    }
    __syncthreads();

    // ---- depthwise 3x3x3 SAME ----
    if (which < 2) {
        f16* slab = Xsh;                       // [512][104]
        unsigned* wdh = wdx;
        const int pos = tid;
        const int d = pos >> 6, h = (pos >> 3) & 7, w = pos & 7;
        int npoff[27]; unsigned vmask[27];
        #pragma unroll
        for (int kd = 0; kd < 3; ++kd)
        #pragma unroll
        for (int kh = 0; kh < 3; ++kh)
        #pragma unroll
        for (int kw = 0; kw < 3; ++kw) {
            int t2 = kd * 9 + kh * 3 + kw;
            int d2 = d + kd - 1, h2 = h + kh - 1, w2 = w + kw - 1;
            bool valid = ((unsigned)d2 < 8u) && ((unsigned)h2 < 8u) && ((unsigned)w2 < 8u);
            int np = d2 * 64 + h2 * 8 + w2;
            npoff[t2] = valid ? np * 104 : 0;
            vmask[t2] = valid ? 0xFFFFFFFFu : 0u;
        }
        f16* outb = ((which == 0) ? qo : ko) + (size_t)b * 512 * 96;
        #pragma unroll
        for (int cc = 0; cc < 12; ++cc) {
            f16x2 a0[4], a1[4], a2[4];
            #pragma unroll
            for (int p = 0; p < 4; ++p) {
                a0[p] = f16x2{0, 0}; a1[p] = f16x2{0, 0}; a2[p] = f16x2{0, 0};
            }
            #pragma unroll
            for (int t2 = 0; t2 < 27; ++t2) {
                U4H rw; rw.q = *(const uint4*)(slab + npoff[t2] + cc * 8);
                unsigned vm = vmask[t2];
                #pragma unroll
                for (int p = 0; p < 4; ++p) {
                    f16x2 w2 = uAsH(wdh[t2 * 48 + cc * 4 + p] & vm);
                    if (t2 / 9 == 0)      a0[p] = rw.h[p] * w2 + a0[p];
                    else if (t2 / 9 == 1) a1[p] = rw.h[p] * w2 + a1[p];
                    else                  a2[p] = rw.h[p] * w2 + a2[p];
                }
            }
            unsigned ow[4];
            #pragma unroll
            for (int p = 0; p < 4; ++p) {
                float lo = (float)a0[p].x + (float)a1[p].x + (float)a2[p].x + bld[cc * 8 + 2 * p];
                float hi = (float)a0[p].y + (float)a1[p].y + (float)a2[p].y + bld[cc * 8 + 2 * p + 1];
                f16x2 hp = { (f16)lo, (f16)hi };
                ow[p] = hAsU(hp);
            }
            *(uint4*)(outb + (size_t)pos * 96 + cc * 8) = make_uint4(ow[0], ow[1], ow[2], ow[3]);
        }
    } else {
        f16* slab = Xsh;                       // [96][520]
        unsigned* wdp = wdx;
        f16* outb = vo + (size_t)b * 96 * 512;
        #pragma unroll
        for (int j = 0; j < 12; ++j) {
            int u = tid + j * 512;
            int c = u >> 6, dh = u & 63;
            int dd = dh >> 3, hh2 = dh & 7;
            f16x2 A0[4], A1[4], A2[4];
            #pragma unroll
            for (int p = 0; p < 4; ++p) {
                A0[p] = f16x2{0, 0}; A1[p] = f16x2{0, 0}; A2[p] = f16x2{0, 0};
            }
            #pragma unroll
            for (int kd = 0; kd < 3; ++kd) {
                int d2 = dd + kd - 1;
                unsigned vd_ = ((unsigned)d2 < 8u) ? 0xFFFFFFFFu : 0u;
                #pragma unroll
                for (int kh = 0; kh < 3; ++kh) {
                    int h2 = hh2 + kh - 1;
                    unsigned vm = ((((unsigned)h2 < 8u) ? 0xFFFFFFFFu : 0u) & vd_);
                    int rowoff = vm ? ((d2 * 8 + h2) * 8) : 0;
                    uint4 rw = *(const uint4*)(slab + c * 520 + rowoff);
                    unsigned r0 = rw.x, r1 = rw.y, r2 = rw.z, r3 = rw.w;
                    unsigned ms0 = r0 << 16;
                    unsigned ms1 = (r1 << 16) | (r0 >> 16);
                    unsigned ms2 = (r2 << 16) | (r1 >> 16);
                    unsigned ms3 = (r3 << 16) | (r2 >> 16);
                    unsigned ms4 = r3 >> 16;
                    int t0 = kd * 9 + kh * 3;
                    f16x2 w0 = uAsH(wdp[c * 27 + t0]     & vm);
                    f16x2 w1 = uAsH(wdp[c * 27 + t0 + 1] & vm);
                    f16x2 w2 = uAsH(wdp[c * 27 + t0 + 2] & vm);
                    f16x2* acc2 = (kd == 0) ? A0 : ((kd == 1) ? A1 : A2);
                    acc2[0] = uAsH(ms0) * w0 + acc2[0];
                    acc2[1] = uAsH(ms1) * w0 + acc2[1];
                    acc2[2] = uAsH(ms2) * w0 + acc2[2];
                    acc2[3] = uAsH(ms3) * w0 + acc2[3];
                    acc2[0] = uAsH(r0) * w1 + acc2[0];
                    acc2[1] = uAsH(r1) * w1 + acc2[1];
                    acc2[2] = uAsH(r2) * w1 + acc2[2];
                    acc2[3] = uAsH(r3) * w1 + acc2[3];
                    acc2[0] = uAsH(ms1) * w2 + acc2[0];
                    acc2[1] = uAsH(ms2) * w2 + acc2[1];
                    acc2[2] = uAsH(ms3) * w2 + acc2[2];
                    acc2[3] = uAsH(ms4) * w2 + acc2[3];
                }
            }
            float bv = bld[c];
            unsigned ow[4];
            #pragma unroll
            for (int p = 0; p < 4; ++p) {
                float lo = (float)A0[p].x + (float)A1[p].x + (float)A2[p].x + bv;
                float hi = (float)A0[p].y + (float)A1[p].y + (float)A2[p].y + bv;
                f16x2 hp = { (f16)lo, (f16)hi };
                ow[p] = hAsU(hp);
            }
            *(uint4*)(outb + c * 512 + dh * 8) = make_uint4(ow[0], ow[1], ow[2], ow[3]);
        }
    }
}

// ---------------------------------------------------------------------------
// K3 (unchanged from round 8): per-batch mega-block attention.
// ---------------------------------------------------------------------------
__global__ __launch_bounds__(512) void k3_attn(
    const f16* __restrict__ qF, const f16* __restrict__ kF, const f16* __restrict__ vF,
    float* __restrict__ outp)
{
    __shared__ __align__(16) f16 Ksh[512 * 104];   // 106496 B
    __shared__ __align__(16) f16 Psh[8 * 1152];    // 8 waves x [16 q][72 k]

    const int tid = threadIdx.x;
    const int b = blockIdx.x;
    const int wv_ = tid >> 6, lane = tid & 63, lr = lane & 15, lk = lane >> 4;

    const f16* qg = qF + ((size_t)b * 512 + wv_ * 64) * 96;
    const f16* kg = kF + (size_t)b * 512 * 96;
    const f16* vg = vF + (size_t)b * 96 * 512;

    const float scl = 0.14724447f;   // log2(e)/sqrt(96), applied post-MFMA

    #pragma unroll
    for (int it = 0; it < 12; ++it) {
        int i = tid * 8 + it * 4096;
        int r = i / 96, c = i % 96;
        *(uint4*)(Ksh + r * 104 + c) = *(const uint4*)(kg + i);
    }

    f16x8 qf[4][3];
    #pragma unroll
    for (int qg2 = 0; qg2 < 4; ++qg2)
        #pragma unroll
        for (int ks3 = 0; ks3 < 3; ++ks3)
            qf[qg2][ks3] = *(const f16x8*)(qg + (qg2 * 16 + lr) * 96 + ks3 * 32 + lk * 8);

    __syncthreads();

    float mx[4] = {-1e30f, -1e30f, -1e30f, -1e30f};
    for (int t = 0; t < 8; ++t) {
        f16x8 kf[3][4];
        #pragma unroll
        for (int ks3 = 0; ks3 < 3; ++ks3)
            #pragma unroll
            for (int f = 0; f < 4; ++f)
                kf[ks3][f] = *(const f16x8*)(Ksh + (t * 64 + f * 16 + lr) * 104 + ks3 * 32 + lk * 8);
        #pragma unroll
        for (int qg2 = 0; qg2 < 4; ++qg2) {
            f32x4 sa[4];
            #pragma unroll
            for (int f = 0; f < 4; ++f) sa[f] = f32x4{0.f, 0.f, 0.f, 0.f};
            #pragma unroll
            for (int ks3 = 0; ks3 < 3; ++ks3)
                #pragma unroll
                for (int f = 0; f < 4; ++f)
                    sa[f] = __builtin_amdgcn_mfma_f32_16x16x32_f16(kf[ks3][f], qf[qg2][ks3], sa[f], 0, 0, 0);
            #pragma unroll
            for (int f = 0; f < 4; ++f)
                mx[qg2] = fmaxf(mx[qg2],
                    fmaxf(fmaxf(sa[f][0], sa[f][1]), fmaxf(sa[f][2], sa[f][3])));
        }
    }
    #pragma unroll
    for (int qg2 = 0; qg2 < 4; ++qg2) {
        mx[qg2] = fmaxf(mx[qg2], __shfl_xor(mx[qg2], 16));
        mx[qg2] = fmaxf(mx[qg2], __shfl_xor(mx[qg2], 32));
    }

    #pragma unroll
    for (int qg2 = 0; qg2 < 4; ++qg2)
        #pragma unroll
        for (int i = 0; i < 3; ++i) asm volatile("" : "+v"(qf[qg2][i]));

    float sum_p[4] = {0.f, 0.f, 0.f, 0.f};
    f32x4 accO[4][6];
    #pragma unroll
    for (int qg2 = 0; qg2 < 4; ++qg2)
        #pragma unroll
        for (int cg = 0; cg < 6; ++cg) accO[qg2][cg] = f32x4{0.f, 0.f, 0.f, 0.f};

    f16* psw = Psh + wv_ * 1152;
    unsigned* psw32 = (unsigned*)psw;

    for (int t = 0; t < 8; ++t) {
        f16x8 vb[2][6];
        #pragma unroll
        for (int ks2 = 0; ks2 < 2; ++ks2)
            #pragma unroll
            for (int cg = 0; cg < 6; ++cg)
                vb[ks2][cg] = *(const f16x8*)(vg + (size_t)(cg * 16 + lr) * 512
                                                 + t * 64 + ks2 * 32 + lk * 8);
        #pragma unroll
        for (int qg2 = 0; qg2 < 4; ++qg2) {
            f32x4 sa[4];
            #pragma unroll
            for (int f = 0; f < 4; ++f) sa[f] = f32x4{0.f, 0.f, 0.f, 0.f};
            #pragma unroll
            for (int ks3 = 0; ks3 < 3; ++ks3)
                #pragma unroll
                for (int f = 0; f < 4; ++f) {
                    f16x8 kf = *(const f16x8*)(Ksh + (t * 64 + f * 16 + lr) * 104 + ks3 * 32 + lk * 8);
                    sa[f] = __builtin_amdgcn_mfma_f32_16x16x32_f16(kf, qf[qg2][ks3], sa[f], 0, 0, 0);
                }
            #pragma unroll
            for (int f = 0; f < 4; ++f) {
                #pragma unroll
                for (int rp = 0; rp < 2; ++rp) {
                    float e0 = __builtin_amdgcn_exp2f((sa[f][2 * rp]     - mx[qg2]) * scl);
                    float e1 = __builtin_amdgcn_exp2f((sa[f][2 * rp + 1] - mx[qg2]) * scl);
                    sum_p[qg2] += e0 + e1;
                    psw32[lr * 36 + f * 8 + lk * 2 + rp] =
                        pAsU(__builtin_amdgcn_cvt_pkrtz(e0, e1));
                }
            }
            #pragma unroll
            for (int ks2 = 0; ks2 < 2; ++ks2) {
                f16x8 pb = *(const f16x8*)(psw + lr * 72 + ks2 * 32 + lk * 8);
                #pragma unroll
                for (int cg = 0; cg < 6; ++cg)
                    accO[qg2][cg] = __builtin_amdgcn_mfma_f32_16x16x32_f16(
                        vb[ks2][cg], pb, accO[qg2][cg], 0, 0, 0);
            }
        }
    }
    #pragma unroll
    for (int qg2 = 0; qg2 < 4; ++qg2) {
        sum_p[qg2] += __shfl_xor(sum_p[qg2], 16);
        sum_p[qg2] += __shfl_xor(sum_p[qg2], 32);
    }

    #pragma unroll
    for (int qg2 = 0; qg2 < 4; ++qg2) {
        const float inv = 1.0f / sum_p[qg2];
        float* og = outp + ((size_t)b * 512 + wv_ * 64 + qg2 * 16 + lr) * 96;
        #pragma unroll
        for (int cg = 0; cg < 6; ++cg) {
            float4 o4 = make_float4(accO[qg2][cg][0] * inv, accO[qg2][cg][1] * inv,
                                    accO[qg2][cg][2] * inv, accO[qg2][cg][3] * inv);
            *(float4*)(og + cg * 16 + lk * 4) = o4;
        }
    }
}

extern "C" void kernel_launch(void* const* d_in, const int* in_sizes, int n_in,
                              void* d_out, int out_size, void* d_ws, size_t ws_size,
                              hipStream_t stream) {
    const float* x   = (const float*)d_in[0];
    const float* wq1 = (const float*)d_in[1];
    const float* bq1 = (const float*)d_in[2];
    const float* wk1 = (const float*)d_in[3];
    const float* bk1 = (const float*)d_in[4];
    const float* wv1 = (const float*)d_in[5];
    const float* bv1 = (const float*)d_in[6];
    const float* wqd = (const float*)d_in[7];
    const float* bqd = (const float*)d_in[8];
    const float* wkd = (const float*)d_in[9];
    const float* bkd = (const float*)d_in[10];
    const float* wvd = (const float*)d_in[11];
    const float* bvd = (const float*)d_in[12];

    f16* ws = (f16*)d_ws;
    f16* q = ws;
    f16* k = ws + PL;
    f16* v = ws + 2 * PL;

    k12_fused<<<dim3(512, 3), 512, 0, stream>>>(x, wq1, bq1, wk1, bk1, wv1, bv1,
                                                wqd, bqd, wkd, bkd, wvd, bvd, q, k, v);
    k3_attn<<<512, 512, 0, stream>>>(q, k, v, (float*)d_out);
}

// Round 10
// 286.008 us; speedup vs baseline: 2.1461x; 1.1515x over previous
//
#include <hip/hip_runtime.h>
#include <math.h>

typedef _Float16 f16;
typedef _Float16 f16x2 __attribute__((ext_vector_type(2)));
typedef _Float16 f16x8 __attribute__((ext_vector_type(8)));
typedef __fp16 fp16x2 __attribute__((ext_vector_type(2)));
typedef float f32x4 __attribute__((ext_vector_type(4)));

union F2U { f16x2 h; fp16x2 p; unsigned u; };
union U4H { uint4 q; f16x2 h[4]; f16 f[8]; };

__device__ __forceinline__ f16x2 uAsH(unsigned u) { F2U c; c.u = u; return c.h; }
__device__ __forceinline__ unsigned hAsU(f16x2 h) { F2U c; c.h = h; return c.u; }
__device__ __forceinline__ unsigned pAsU(fp16x2 p) { F2U c; c.p = p; return c.u; }

constexpr size_t PL = (size_t)512 * 512 * 96;

// ---------------------------------------------------------------------------
// K12: fused pointwise(1x1x1, MFMA GEMM) + depthwise(3x3x3 SAME) conv.
// grid (512 batches, 3 convs), block 512 (8 waves).
// q/k: swapped-operand GEMM -> channel-quad writeback (uint2); depthwise via
// w-row stencil units (8 row-reads serve 8 outputs; 3x fewer LDS reads).
// v: GEMM -> [ch][pos] writeback; shift-register depthwise (unchanged).
// Outputs: q,k as [b][n][c]; v as [b][c][n].
// ---------------------------------------------------------------------------
__global__ __launch_bounds__(512) void k12_fused(
    const float* __restrict__ x,
    const float* __restrict__ wq1, const float* __restrict__ bq1,
    const float* __restrict__ wk1, const float* __restrict__ bk1,
    const float* __restrict__ wv1, const float* __restrict__ bv1,
    const float* __restrict__ wqd, const float* __restrict__ bqd,
    const float* __restrict__ wkd, const float* __restrict__ bkd,
    const float* __restrict__ wvd, const float* __restrict__ bvd,
    f16* __restrict__ qo, f16* __restrict__ ko, f16* __restrict__ vo)
{
    __shared__ __align__(16) char sm[137600];
    f16* Xsh = (f16*)sm;                       // [512][104] f16; overlaid post-GEMM
    f16* Wsh = (f16*)(sm + 106496);            // [96][104] f16 pointwise w
    unsigned* wdx = (unsigned*)(sm + 126464);  // q/k: [27][48] u32; v: [96][27] u32
    float* bl1 = (float*)(sm + 136832);        // [96] pointwise bias
    float* bld = (float*)(sm + 137216);        // [96] depthwise bias

    const int tid = threadIdx.x;
    const int b = blockIdx.x;
    const int which = blockIdx.y;
    const int wv_ = tid >> 6, lane = tid & 63, lr = lane & 15, lk = lane >> 4;

    const float* w1 = (which == 0) ? wq1 : ((which == 1) ? wk1 : wv1);
    const float* b1 = (which == 0) ? bq1 : ((which == 1) ? bk1 : bv1);
    const float* wd = (which == 0) ? wqd : ((which == 1) ? wkd : wvd);
    const float* bd = (which == 0) ? bqd : ((which == 1) ? bkd : bvd);

    // ---- stage x (f32->f16), pointwise w, depthwise w, biases ----
    const float* xb = x + (size_t)b * 512 * 96;
    #pragma unroll
    for (int it = 0; it < 24; ++it) {
        int i = (tid + it * 512) * 4;
        float4 v4 = *(const float4*)(xb + i);
        int r = i / 96, c = i % 96;
        f16x2 h01 = { (f16)v4.x, (f16)v4.y };
        f16x2 h23 = { (f16)v4.z, (f16)v4.w };
        uint2 st; st.x = hAsU(h01); st.y = hAsU(h23);
        *(uint2*)(Xsh + r * 104 + c) = st;
    }
    #pragma unroll
    for (int it = 0; it < 5; ++it) {
        int i = (tid + it * 512) * 4;
        if (i < 9216) {
            float4 v4 = *(const float4*)(w1 + i);
            int co = i / 96, ci = i % 96;
            f16x2 h01 = { (f16)v4.x, (f16)v4.y };
            f16x2 h23 = { (f16)v4.z, (f16)v4.w };
            uint2 st; st.x = hAsU(h01); st.y = hAsU(h23);
            *(uint2*)(Wsh + co * 104 + ci) = st;
        }
    }
    if (which < 2) {
        for (int ii = tid; ii < 2592; ii += 512) {
            int c = ii / 27, t2 = ii % 27;
            ((f16*)wdx)[t2 * 96 + c] = (f16)wd[ii];
        }
    } else {
        for (int ii = tid; ii < 2592; ii += 512) {
            int c = ii / 27, t2 = ii % 27;
            f16 hh = (f16)wd[ii];
            f16x2 hp = { hh, hh };
            wdx[c * 27 + t2] = hAsU(hp);
        }
    }
    if (tid < 96) { bl1[tid] = b1[tid]; bld[tid] = bd[tid]; }
    __syncthreads();

    // ---- pointwise GEMM ----
    f32x4 acc[4][6];
    #pragma unroll
    for (int pg = 0; pg < 4; ++pg)
        #pragma unroll
        for (int cg = 0; cg < 6; ++cg) acc[pg][cg] = f32x4{0.f, 0.f, 0.f, 0.f};

    if (which < 2) {
        // swapped operands: C[ch][pos] -> lane: pos=lr, ch-quad = cg*16+lk*4+reg
        #pragma unroll
        for (int ks = 0; ks < 3; ++ks) {
            f16x8 bfr[6];
            #pragma unroll
            for (int cg = 0; cg < 6; ++cg)
                bfr[cg] = *(const f16x8*)(Wsh + (cg * 16 + lr) * 104 + ks * 32 + lk * 8);
            #pragma unroll
            for (int pg = 0; pg < 4; ++pg) {
                f16x8 a = *(const f16x8*)(Xsh + (wv_ * 64 + pg * 16 + lr) * 104 + ks * 32 + lk * 8);
                #pragma unroll
                for (int cg = 0; cg < 6; ++cg)
                    acc[pg][cg] = __builtin_amdgcn_mfma_f32_16x16x32_f16(bfr[cg], a, acc[pg][cg], 0, 0, 0);
            }
        }
    } else {
        #pragma unroll
        for (int ks = 0; ks < 3; ++ks) {
            f16x8 bfr[6];
            #pragma unroll
            for (int cg = 0; cg < 6; ++cg)
                bfr[cg] = *(const f16x8*)(Wsh + (cg * 16 + lr) * 104 + ks * 32 + lk * 8);
            #pragma unroll
            for (int pg = 0; pg < 4; ++pg) {
                f16x8 a = *(const f16x8*)(Xsh + (wv_ * 64 + pg * 16 + lr) * 104 + ks * 32 + lk * 8);
                #pragma unroll
                for (int cg = 0; cg < 6; ++cg)
                    acc[pg][cg] = __builtin_amdgcn_mfma_f32_16x16x32_f16(a, bfr[cg], acc[pg][cg], 0, 0, 0);
            }
        }
    }
    __syncthreads();   // all Xsh reads done before overlay

    // ---- write GEMM out (+bias) over the slab ----
    if (which < 2) {
        // [pos][ch] stride 104: 4 consecutive channels per reg-quad -> uint2
        #pragma unroll
        for (int pg = 0; pg < 4; ++pg) {
            #pragma unroll
            for (int cg = 0; cg < 6; ++cg) {
                float4 bv4 = *(const float4*)&bl1[cg * 16 + lk * 4];
                int pos = wv_ * 64 + pg * 16 + lr;
                f16x2 h01 = { (f16)(acc[pg][cg][0] + bv4.x), (f16)(acc[pg][cg][1] + bv4.y) };
                f16x2 h23 = { (f16)(acc[pg][cg][2] + bv4.z), (f16)(acc[pg][cg][3] + bv4.w) };
                uint2 st; st.x = hAsU(h01); st.y = hAsU(h23);
                *(uint2*)(Xsh + pos * 104 + cg * 16 + lk * 4) = st;
            }
        }
    } else {
        // [ch][pos] stride 520: 4 consecutive positions per reg-quad -> uint2
        #pragma unroll
        for (int pg = 0; pg < 4; ++pg) {
            #pragma unroll
            for (int cg = 0; cg < 6; ++cg) {
                float bv = bl1[cg * 16 + lr];
                int ch = cg * 16 + lr;
                int pos = wv_ * 64 + pg * 16 + lk * 4;
                f16x2 h01 = { (f16)(acc[pg][cg][0] + bv), (f16)(acc[pg][cg][1] + bv) };
                f16x2 h23 = { (f16)(acc[pg][cg][2] + bv), (f16)(acc[pg][cg][3] + bv) };
                uint2 st; st.x = hAsU(h01); st.y = hAsU(h23);
                *(uint2*)(Xsh + ch * 520 + pos) = st;
            }
        }
    }
    __syncthreads();

    // ---- depthwise 3x3x3 SAME ----
    if (which < 2) {
        // unit = (w-row r=(d,h), 8-channel group g). 768 units over 512 threads.
        f16* slab = Xsh;                       // [512][104] pointwise output
        unsigned* wdh = wdx;                   // [27][48] channel-pair weights
        f16* outb = ((which == 0) ? qo : ko) + (size_t)b * 512 * 96;
        #pragma unroll
        for (int half = 0; half < 2; ++half) {
            if (half == 1 && tid >= 256) break;
            const int u = half * 512 + tid;
            const int r = u / 12;
            const int g = u - r * 12;
            const int dd = r >> 3, hh = r & 7;
            const int col = g * 8;
            float mo[8][8];
            {
                float4 b0 = *(const float4*)&bld[col];
                float4 b1_ = *(const float4*)&bld[col + 4];
                #pragma unroll
                for (int w = 0; w < 8; ++w) {
                    mo[w][0] = b0.x;  mo[w][1] = b0.y;  mo[w][2] = b0.z;  mo[w][3] = b0.w;
                    mo[w][4] = b1_.x; mo[w][5] = b1_.y; mo[w][6] = b1_.z; mo[w][7] = b1_.w;
                }
            }
            #pragma unroll
            for (int kd = 0; kd < 3; ++kd) {
                const int d2 = dd + kd - 1;
                const bool vd = (unsigned)d2 < 8u;
                f16x2 pa[8][4];
                #pragma unroll
                for (int w = 0; w < 8; ++w)
                    #pragma unroll
                    for (int p = 0; p < 4; ++p) pa[w][p] = f16x2{0, 0};
                #pragma unroll
                for (int kh = 0; kh < 3; ++kh) {
                    const int h2 = hh + kh - 1;
                    const unsigned vm = (vd && ((unsigned)h2 < 8u)) ? 0xFFFFFFFFu : 0u;
                    const int base = (vm ? (d2 * 64 + h2 * 8) : 0) * 104 + col;
                    U4H in[8];
                    #pragma unroll
                    for (int w2 = 0; w2 < 8; ++w2)
                        in[w2].q = *(const uint4*)(slab + base + w2 * 104);
                    const int t0 = (kd * 3 + kh) * 3;
                    f16x2 wt0[4], wt1[4], wt2[4];
                    #pragma unroll
                    for (int p = 0; p < 4; ++p) {
                        wt0[p] = uAsH(wdh[(t0 + 0) * 48 + g * 4 + p] & vm);
                        wt1[p] = uAsH(wdh[(t0 + 1) * 48 + g * 4 + p] & vm);
                        wt2[p] = uAsH(wdh[(t0 + 2) * 48 + g * 4 + p] & vm);
                    }
                    #pragma unroll
                    for (int w = 0; w < 8; ++w) {
                        #pragma unroll
                        for (int p = 0; p < 4; ++p) {
                            f16x2 s = pa[w][p];
                            s = in[w].h[p] * wt1[p] + s;
                            if (w > 0) s = in[w - 1].h[p] * wt0[p] + s;
                            if (w < 7) s = in[w + 1].h[p] * wt2[p] + s;
                            pa[w][p] = s;
                        }
                    }
                }
                #pragma unroll
                for (int w = 0; w < 8; ++w)
                    #pragma unroll
                    for (int p = 0; p < 4; ++p) {
                        mo[w][2 * p]     += (float)pa[w][p].x;
                        mo[w][2 * p + 1] += (float)pa[w][p].y;
                    }
            }
            #pragma unroll
            for (int w = 0; w < 8; ++w) {
                f16x2 h0 = { (f16)mo[w][0], (f16)mo[w][1] };
                f16x2 h1 = { (f16)mo[w][2], (f16)mo[w][3] };
                f16x2 h2 = { (f16)mo[w][4], (f16)mo[w][5] };
                f16x2 h3 = { (f16)mo[w][6], (f16)mo[w][7] };
                *(uint4*)(outb + (size_t)(r * 8 + w) * 96 + col) =
                    make_uint4(hAsU(h0), hAsU(h1), hAsU(h2), hAsU(h3));
            }
        }
    } else {
        f16* slab = Xsh;                       // [96][520]
        unsigned* wdp = wdx;
        f16* outb = vo + (size_t)b * 96 * 512;
        #pragma unroll
        for (int j = 0; j < 12; ++j) {
            int u = tid + j * 512;
            int c = u >> 6, dh = u & 63;
            int dd = dh >> 3, hh2 = dh & 7;
            f16x2 A0[4], A1[4], A2[4];
            #pragma unroll
            for (int p = 0; p < 4; ++p) {
                A0[p] = f16x2{0, 0}; A1[p] = f16x2{0, 0}; A2[p] = f16x2{0, 0};
            }
            #pragma unroll
            for (int kd = 0; kd < 3; ++kd) {
                int d2 = dd + kd - 1;
                unsigned vd_ = ((unsigned)d2 < 8u) ? 0xFFFFFFFFu : 0u;
                #pragma unroll
                for (int kh = 0; kh < 3; ++kh) {
                    int h2 = hh2 + kh - 1;
                    unsigned vm = ((((unsigned)h2 < 8u) ? 0xFFFFFFFFu : 0u) & vd_);
                    int rowoff = vm ? ((d2 * 8 + h2) * 8) : 0;
                    uint4 rw = *(const uint4*)(slab + c * 520 + rowoff);
                    unsigned r0 = rw.x, r1 = rw.y, r2 = rw.z, r3 = rw.w;
                    unsigned ms0 = r0 << 16;
                    unsigned ms1 = (r1 << 16) | (r0 >> 16);
                    unsigned ms2 = (r2 << 16) | (r1 >> 16);
                    unsigned ms3 = (r3 << 16) | (r2 >> 16);
                    unsigned ms4 = r3 >> 16;
                    int t0 = kd * 9 + kh * 3;
                    f16x2 w0 = uAsH(wdp[c * 27 + t0]     & vm);
                    f16x2 w1 = uAsH(wdp[c * 27 + t0 + 1] & vm);
                    f16x2 w2 = uAsH(wdp[c * 27 + t0 + 2] & vm);
                    f16x2* acc2 = (kd == 0) ? A0 : ((kd == 1) ? A1 : A2);
                    acc2[0] = uAsH(ms0) * w0 + acc2[0];
                    acc2[1] = uAsH(ms1) * w0 + acc2[1];
                    acc2[2] = uAsH(ms2) * w0 + acc2[2];
                    acc2[3] = uAsH(ms3) * w0 + acc2[3];
                    acc2[0] = uAsH(r0) * w1 + acc2[0];
                    acc2[1] = uAsH(r1) * w1 + acc2[1];
                    acc2[2] = uAsH(r2) * w1 + acc2[2];
                    acc2[3] = uAsH(r3) * w1 + acc2[3];
                    acc2[0] = uAsH(ms1) * w2 + acc2[0];
                    acc2[1] = uAsH(ms2) * w2 + acc2[1];
                    acc2[2] = uAsH(ms3) * w2 + acc2[2];
                    acc2[3] = uAsH(ms4) * w2 + acc2[3];
                }
            }
            float bv = bld[c];
            unsigned ow[4];
            #pragma unroll
            for (int p = 0; p < 4; ++p) {
                float lo = (float)A0[p].x + (float)A1[p].x + (float)A2[p].x + bv;
                float hi = (float)A0[p].y + (float)A1[p].y + (float)A2[p].y + bv;
                f16x2 hp = { (f16)lo, (f16)hi };
                ow[p] = hAsU(hp);
            }
            *(uint4*)(outb + c * 512 + dh * 8) = make_uint4(ow[0], ow[1], ow[2], ow[3]);
        }
    }
}

// ---------------------------------------------------------------------------
// K3 v5: per-batch mega-block attention. Pass-2 now hoists kf (12 LDS reads/t
// instead of 48) and vb; streams qf fragments from global (L1/L2-hot).
// P written as uint2 pairs. grid 512, block 512 (8 waves x 64 q-rows).
// ---------------------------------------------------------------------------
__global__ __launch_bounds__(512) void k3_attn(
    const f16* __restrict__ qF, const f16* __restrict__ kF, const f16* __restrict__ vF,
    float* __restrict__ outp)
{
    __shared__ __align__(16) f16 Ksh[512 * 104];   // 106496 B
    __shared__ __align__(16) f16 Psh[8 * 1152];    // 8 waves x [16 q][72 k]

    const int tid = threadIdx.x;
    const int b = blockIdx.x;
    const int wv_ = tid >> 6, lane = tid & 63, lr = lane & 15, lk = lane >> 4;

    const f16* qg = qF + ((size_t)b * 512 + wv_ * 64) * 96;
    const f16* kg = kF + (size_t)b * 512 * 96;
    const f16* vg = vF + (size_t)b * 96 * 512;

    const float scl = 0.14724447f;   // log2(e)/sqrt(96), applied post-MFMA

    #pragma unroll
    for (int it = 0; it < 12; ++it) {
        int i = tid * 8 + it * 4096;
        int r = i / 96, c = i % 96;
        *(uint4*)(Ksh + r * 104 + c) = *(const uint4*)(kg + i);
    }

    // Q fragments hoisted for pass 1 only (dead before pass 2)
    f16x8 qf[4][3];
    #pragma unroll
    for (int qg2 = 0; qg2 < 4; ++qg2)
        #pragma unroll
        for (int ks3 = 0; ks3 < 3; ++ks3)
            qf[qg2][ks3] = *(const f16x8*)(qg + (qg2 * 16 + lr) * 96 + ks3 * 32 + lk * 8);

    __syncthreads();

    // ---- pass 1: global row max ----
    float mx[4] = {-1e30f, -1e30f, -1e30f, -1e30f};
    for (int t = 0; t < 8; ++t) {
        f16x8 kf[3][4];
        #pragma unroll
        for (int ks3 = 0; ks3 < 3; ++ks3)
            #pragma unroll
            for (int f = 0; f < 4; ++f)
                kf[ks3][f] = *(const f16x8*)(Ksh + (t * 64 + f * 16 + lr) * 104 + ks3 * 32 + lk * 8);
        #pragma unroll
        for (int qg2 = 0; qg2 < 4; ++qg2) {
            f32x4 sa[4];
            #pragma unroll
            for (int f = 0; f < 4; ++f) sa[f] = f32x4{0.f, 0.f, 0.f, 0.f};
            #pragma unroll
            for (int ks3 = 0; ks3 < 3; ++ks3)
                #pragma unroll
                for (int f = 0; f < 4; ++f)
                    sa[f] = __builtin_amdgcn_mfma_f32_16x16x32_f16(kf[ks3][f], qf[qg2][ks3], sa[f], 0, 0, 0);
            #pragma unroll
            for (int f = 0; f < 4; ++f)
                mx[qg2] = fmaxf(mx[qg2],
                    fmaxf(fmaxf(sa[f][0], sa[f][1]), fmaxf(sa[f][2], sa[f][3])));
        }
    }
    #pragma unroll
    for (int qg2 = 0; qg2 < 4; ++qg2) {
        mx[qg2] = fmaxf(mx[qg2], __shfl_xor(mx[qg2], 16));
        mx[qg2] = fmaxf(mx[qg2], __shfl_xor(mx[qg2], 32));
    }

    // compiler barrier: pass-2 loads are fresh, no CSE with pass-1 chains
    asm volatile("" ::: "memory");

    // ---- pass 2: recompute QK, exp with fixed max, PV ----
    float sum_p[4] = {0.f, 0.f, 0.f, 0.f};
    f32x4 accO[4][6];
    #pragma unroll
    for (int qg2 = 0; qg2 < 4; ++qg2)
        #pragma unroll
        for (int cg = 0; cg < 6; ++cg) accO[qg2][cg] = f32x4{0.f, 0.f, 0.f, 0.f};

    f16* psw = Psh + wv_ * 1152;
    uint2* psw2 = (uint2*)psw;

    for (int t = 0; t < 8; ++t) {
        f16x8 kf2[3][4];
        #pragma unroll
        for (int ks3 = 0; ks3 < 3; ++ks3)
            #pragma unroll
            for (int f = 0; f < 4; ++f)
                kf2[ks3][f] = *(const f16x8*)(Ksh + (t * 64 + f * 16 + lr) * 104 + ks3 * 32 + lk * 8);
        f16x8 vb[2][6];
        #pragma unroll
        for (int ks2 = 0; ks2 < 2; ++ks2)
            #pragma unroll
            for (int cg = 0; cg < 6; ++cg)
                vb[ks2][cg] = *(const f16x8*)(vg + (size_t)(cg * 16 + lr) * 512
                                                 + t * 64 + ks2 * 32 + lk * 8);
        #pragma unroll
        for (int qg2 = 0; qg2 < 4; ++qg2) {
            f16x8 qf3[3];
            #pragma unroll
            for (int ks3 = 0; ks3 < 3; ++ks3)
                qf3[ks3] = *(const f16x8*)(qg + (qg2 * 16 + lr) * 96 + ks3 * 32 + lk * 8);
            f32x4 sa[4];
            #pragma unroll
            for (int f = 0; f < 4; ++f) sa[f] = f32x4{0.f, 0.f, 0.f, 0.f};
            #pragma unroll
            for (int ks3 = 0; ks3 < 3; ++ks3)
                #pragma unroll
                for (int f = 0; f < 4; ++f)
                    sa[f] = __builtin_amdgcn_mfma_f32_16x16x32_f16(kf2[ks3][f], qf3[ks3], sa[f], 0, 0, 0);
            #pragma unroll
            for (int f = 0; f < 4; ++f) {
                float e0 = __builtin_amdgcn_exp2f((sa[f][0] - mx[qg2]) * scl);
                float e1 = __builtin_amdgcn_exp2f((sa[f][1] - mx[qg2]) * scl);
                float e2 = __builtin_amdgcn_exp2f((sa[f][2] - mx[qg2]) * scl);
                float e3 = __builtin_amdgcn_exp2f((sa[f][3] - mx[qg2]) * scl);
                sum_p[qg2] += (e0 + e1) + (e2 + e3);
                uint2 pk;
                pk.x = pAsU(__builtin_amdgcn_cvt_pkrtz(e0, e1));
                pk.y = pAsU(__builtin_amdgcn_cvt_pkrtz(e2, e3));
                psw2[lr * 18 + f * 4 + lk] = pk;
            }
            #pragma unroll
            for (int ks2 = 0; ks2 < 2; ++ks2) {
                f16x8 pb = *(const f16x8*)(psw + lr * 72 + ks2 * 32 + lk * 8);
                #pragma unroll
                for (int cg = 0; cg < 6; ++cg)
                    accO[qg2][cg] = __builtin_amdgcn_mfma_f32_16x16x32_f16(
                        vb[ks2][cg], pb, accO[qg2][cg], 0, 0, 0);
            }
        }
    }
    #pragma unroll
    for (int qg2 = 0; qg2 < 4; ++qg2) {
        sum_p[qg2] += __shfl_xor(sum_p[qg2], 16);
        sum_p[qg2] += __shfl_xor(sum_p[qg2], 32);
    }

    #pragma unroll
    for (int qg2 = 0; qg2 < 4; ++qg2) {
        const float inv = 1.0f / sum_p[qg2];
        float* og = outp + ((size_t)b * 512 + wv_ * 64 + qg2 * 16 + lr) * 96;
        #pragma unroll
        for (int cg = 0; cg < 6; ++cg) {
            float4 o4 = make_float4(accO[qg2][cg][0] * inv, accO[qg2][cg][1] * inv,
                                    accO[qg2][cg][2] * inv, accO[qg2][cg][3] * inv);
            *(float4*)(og + cg * 16 + lk * 4) = o4;
        }
    }
}

extern "C" void kernel_launch(void* const* d_in, const int* in_sizes, int n_in,
                              void* d_out, int out_size, void* d_ws, size_t ws_size,
                              hipStream_t stream) {
    const float* x   = (const float*)d_in[0];
    const float* wq1 = (const float*)d_in[1];
    const float* bq1 = (const float*)d_in[2];
    const float* wk1 = (const float*)d_in[3];
    const float* bk1 = (const float*)d_in[4];
    const float* wv1 = (const float*)d_in[5];
    const float* bv1 = (const float*)d_in[6];
    const float* wqd = (const float*)d_in[7];
    const float* bqd = (const float*)d_in[8];
    const float* wkd = (const float*)d_in[9];
    const float* bkd = (const float*)d_in[10];
    const float* wvd = (const float*)d_in[11];
    const float* bvd = (const float*)d_in[12];

    f16* ws = (f16*)d_ws;
    f16* q = ws;
    f16* k = ws + PL;
    f16* v = ws + 2 * PL;

    k12_fused<<<dim3(512, 3), 512, 0, stream>>>(x, wq1, bq1, wk1, bk1, wv1, bv1,
                                                wqd, bqd, wkd, bkd, wvd, bvd, q, k, v);
    k3_attn<<<512, 512, 0, stream>>>(q, k, v, (float*)d_out);
}